// Round 1
// baseline (10502.554 us; speedup 1.0000x reference)
//
#include <hip/hip_runtime.h>

// Precoding GNN: 5 layers of z = Ws*x + Wm*(sum_k x) + Wk*(sum_m x), ReLU(1-4),
// then Frobenius power normalization per batch item.
// M=64 antennas, K=32 users, D=32 hidden, BS=1024.
//
// Design: one 1024-thread block per batch item. Thread t owns nodes t and
// t+1024 (node n = m*32+k), all 32 features in registers (fp32 end-to-end).
// msg_m via shfl_xor butterfly over the 32 lanes sharing m; msg_k via pair
// add + shfl_xor(32) + LDS fp32 atomics across the 16 waves.

namespace {

constexpr int NTHREADS = 1024;

template <int DIN, int DOUT, bool RELU>
__device__ __forceinline__ void gnn_layer_dev(
    float* __restrict__ x1, float* __restrict__ x2,
    const float* __restrict__ Wsg, const float* __restrict__ Wmg,
    const float* __restrict__ Wkg,
    float* __restrict__ Ws_l,   // [DOUT*DIN] unpadded (uniform/broadcast reads)
    float* __restrict__ Wm_l,   // [32*33] padded rows
    float* __restrict__ Wk_l,   // [32*33] padded rows
    float* __restrict__ Abuf,   // [64*33]
    float* __restrict__ Bbuf,   // [32*33]
    float* __restrict__ msgk,   // [32*33]
    int t, int k, int m1, int m2, int lane)
{
    // ---- phase 0: stage weights to LDS, zero msg_k accumulator ----
    for (int i = t; i < DOUT * DIN; i += NTHREADS) {
        const int h = i / DIN, d = i % DIN;
        Ws_l[i] = Wsg[i];
        Wm_l[h * 33 + d] = Wmg[i];
        Wk_l[h * 33 + d] = Wkg[i];
    }
    for (int i = t; i < 32 * 33; i += NTHREADS) msgk[i] = 0.0f;
    __syncthreads();

    // ---- phase 1: msg_m butterfly (+fused A = Wm*msg_m), msg_k atomics ----
    {
        float mm[DIN];
        // node set 1 (antenna m1): lanes (t & ~31)..(t|31) all share m1
#pragma unroll
        for (int d = 0; d < DIN; ++d) mm[d] = x1[d];
#pragma unroll
        for (int mask = 1; mask <= 16; mask <<= 1) {
#pragma unroll
            for (int d = 0; d < DIN; ++d) mm[d] += __shfl_xor(mm[d], mask);
        }
        if (k < DOUT) {
            float acc = 0.0f;
#pragma unroll
            for (int d = 0; d < DIN; ++d) acc += Wm_l[k * 33 + d] * mm[d];
            Abuf[m1 * 33 + k] = acc;
        }
        // node set 2 (antenna m2 = m1+32)
#pragma unroll
        for (int d = 0; d < DIN; ++d) mm[d] = x2[d];
#pragma unroll
        for (int mask = 1; mask <= 16; mask <<= 1) {
#pragma unroll
            for (int d = 0; d < DIN; ++d) mm[d] += __shfl_xor(mm[d], mask);
        }
        if (k < DOUT) {
            float acc = 0.0f;
#pragma unroll
            for (int d = 0; d < DIN; ++d) acc += Wm_l[k * 33 + d] * mm[d];
            Abuf[m2 * 33 + k] = acc;
        }
        // msg_k: this thread holds 2 of the 64 antennas for user k; lane^32
        // holds 2 more; 16 waves cover all 64 via LDS atomics.
#pragma unroll
        for (int d = 0; d < DIN; ++d) {
            float s = x1[d] + x2[d];
            s += __shfl_xor(s, 32);
            if (lane < 32) atomicAdd(&msgk[k * 33 + d], s);
        }
    }
    __syncthreads();

    // ---- phase 2: B[k][h] = Wk * msg_k ----
    if (t < 32 * DOUT) {
        const int kk = t / DOUT, hh = t % DOUT;
        float acc = 0.0f;
#pragma unroll
        for (int d = 0; d < DIN; ++d) acc += Wk_l[hh * 33 + d] * msgk[kk * 33 + d];
        Bbuf[kk * 33 + hh] = acc;
    }
    __syncthreads();

    // ---- phase 3: per-node z = Ws*x + A[m] + B[k], relu, x <- z ----
    {
        float z[DOUT];
#pragma unroll
        for (int h = 0; h < DOUT; ++h) {
            float acc = Abuf[m1 * 33 + h] + Bbuf[k * 33 + h];
            if constexpr (DIN >= 4) {
                const float4* wr = reinterpret_cast<const float4*>(Ws_l + h * DIN);
#pragma unroll
                for (int q = 0; q < DIN / 4; ++q) {
                    const float4 w = wr[q];
                    acc += w.x * x1[4 * q] + w.y * x1[4 * q + 1]
                         + w.z * x1[4 * q + 2] + w.w * x1[4 * q + 3];
                }
            } else {
#pragma unroll
                for (int d = 0; d < DIN; ++d) acc += Ws_l[h * DIN + d] * x1[d];
            }
            z[h] = RELU ? fmaxf(acc, 0.0f) : acc;
        }
#pragma unroll
        for (int h = 0; h < DOUT; ++h) x1[h] = z[h];

#pragma unroll
        for (int h = 0; h < DOUT; ++h) {
            float acc = Abuf[m2 * 33 + h] + Bbuf[k * 33 + h];
            if constexpr (DIN >= 4) {
                const float4* wr = reinterpret_cast<const float4*>(Ws_l + h * DIN);
#pragma unroll
                for (int q = 0; q < DIN / 4; ++q) {
                    const float4 w = wr[q];
                    acc += w.x * x2[4 * q] + w.y * x2[4 * q + 1]
                         + w.z * x2[4 * q + 2] + w.w * x2[4 * q + 3];
                }
            } else {
#pragma unroll
                for (int d = 0; d < DIN; ++d) acc += Ws_l[h * DIN + d] * x2[d];
            }
            z[h] = RELU ? fmaxf(acc, 0.0f) : acc;
        }
#pragma unroll
        for (int h = 0; h < DOUT; ++h) x2[h] = z[h];
    }
    __syncthreads();  // protect W/msgk LDS before next layer restages
}

__global__ __launch_bounds__(NTHREADS) void gnn_fused(
    const float* __restrict__ xg,
    const float* __restrict__ w1s, const float* __restrict__ w1m, const float* __restrict__ w1k,
    const float* __restrict__ w2s, const float* __restrict__ w2m, const float* __restrict__ w2k,
    const float* __restrict__ w3s, const float* __restrict__ w3m, const float* __restrict__ w3k,
    const float* __restrict__ w4s, const float* __restrict__ w4m, const float* __restrict__ w4k,
    const float* __restrict__ w5s, const float* __restrict__ w5m, const float* __restrict__ w5k,
    float* __restrict__ out)
{
    __shared__ float Ws_l[32 * 32];
    __shared__ float Wm_l[32 * 33];
    __shared__ float Wk_l[32 * 33];
    __shared__ float Abuf[64 * 33];
    __shared__ float Bbuf[32 * 33];
    __shared__ float msgk[32 * 33];
    __shared__ float red[17];

    const int t = threadIdx.x;
    const int b = blockIdx.x;
    const int k = t & 31;
    const int m1 = t >> 5;
    const int m2 = m1 + 32;
    const int lane = t & 63;
    const int wave = t >> 6;

    float x1[32], x2[32];

    // input: (b, 64, 32, 2) -> node n covers floats [2n, 2n+1]
    const float2 a1 = *reinterpret_cast<const float2*>(xg + (size_t)b * 4096 + 2 * t);
    const float2 a2 = *reinterpret_cast<const float2*>(xg + (size_t)b * 4096 + 2048 + 2 * t);
    x1[0] = a1.x; x1[1] = a1.y;
    x2[0] = a2.x; x2[1] = a2.y;

    gnn_layer_dev<2, 32, true>(x1, x2, w1s, w1m, w1k,
                               Ws_l, Wm_l, Wk_l, Abuf, Bbuf, msgk, t, k, m1, m2, lane);

#pragma unroll 1
    for (int l = 0; l < 3; ++l) {
        const float* ws = (l == 0) ? w2s : (l == 1) ? w3s : w4s;
        const float* wm = (l == 0) ? w2m : (l == 1) ? w3m : w4m;
        const float* wk = (l == 0) ? w2k : (l == 1) ? w3k : w4k;
        gnn_layer_dev<32, 32, true>(x1, x2, ws, wm, wk,
                                    Ws_l, Wm_l, Wk_l, Abuf, Bbuf, msgk, t, k, m1, m2, lane);
    }

    gnn_layer_dev<32, 2, false>(x1, x2, w5s, w5m, w5k,
                                Ws_l, Wm_l, Wk_l, Abuf, Bbuf, msgk, t, k, m1, m2, lane);

    // ---- pwr_norm: alpha = rsqrt(sum over all (m,k,c) of z^2) ----
    float p = x1[0] * x1[0] + x1[1] * x1[1] + x2[0] * x2[0] + x2[1] * x2[1];
#pragma unroll
    for (int mask = 1; mask <= 32; mask <<= 1) p += __shfl_xor(p, mask);
    if (lane == 0) red[wave] = p;
    __syncthreads();
    if (t == 0) {
        float tot = 0.0f;
#pragma unroll
        for (int i = 0; i < 16; ++i) tot += red[i];
        red[16] = rsqrtf(tot);
    }
    __syncthreads();
    const float alpha = red[16];

    float2 o1, o2;
    o1.x = alpha * x1[0]; o1.y = alpha * x1[1];
    o2.x = alpha * x2[0]; o2.y = alpha * x2[1];
    *reinterpret_cast<float2*>(out + (size_t)b * 4096 + 2 * t) = o1;
    *reinterpret_cast<float2*>(out + (size_t)b * 4096 + 2048 + 2 * t) = o2;
}

}  // namespace

extern "C" void kernel_launch(void* const* d_in, const int* in_sizes, int n_in,
                              void* d_out, int out_size, void* d_ws, size_t ws_size,
                              hipStream_t stream) {
    const float* xg  = (const float*)d_in[0];
    const float* w1s = (const float*)d_in[1];
    const float* w1m = (const float*)d_in[2];
    const float* w1k = (const float*)d_in[3];
    const float* w2s = (const float*)d_in[4];
    const float* w2m = (const float*)d_in[5];
    const float* w2k = (const float*)d_in[6];
    const float* w3s = (const float*)d_in[7];
    const float* w3m = (const float*)d_in[8];
    const float* w3k = (const float*)d_in[9];
    const float* w4s = (const float*)d_in[10];
    const float* w4m = (const float*)d_in[11];
    const float* w4k = (const float*)d_in[12];
    const float* w5s = (const float*)d_in[13];
    const float* w5m = (const float*)d_in[14];
    const float* w5k = (const float*)d_in[15];
    float* out = (float*)d_out;

    hipLaunchKernelGGL(gnn_fused, dim3(1024), dim3(NTHREADS), 0, stream,
                       xg, w1s, w1m, w1k, w2s, w2m, w2k, w3s, w3m, w3k,
                       w4s, w4m, w4k, w5s, w5m, w5k, out);
}

// Round 2
// 2388.604 us; speedup vs baseline: 4.3969x; 4.3969x over previous
//
#include <hip/hip_runtime.h>

// Precoding GNN: 5 layers of z = Ws*x + Wm*(sum_k x) + Wk*(sum_m x), ReLU(1-4),
// then Frobenius power normalization per batch item.
// M=64 antennas, K=32 users, D=32 hidden, BS=1024.
//
// One 1024-thread block per batch item. Thread t owns nodes t and t+1024
// (node n = m*32+k), all 32 features in registers, fp32 end-to-end.
//
// R1 lesson: __launch_bounds__(1024) alone let the backend target 8 waves/EU
// -> 64-VGPR budget -> ~96-float working set spilled to scratch -> 34 GB of
// HBM traffic. A 1024-thread block can never exceed 4 waves/EU per block
// anyway, so declare (1024, 4) to get the 128-VGPR budget and keep x1/x2/mm
// in registers.

namespace {

constexpr int NTHREADS = 1024;

template <int DIN, int DOUT, bool RELU>
__device__ __forceinline__ void gnn_layer_dev(
    float* __restrict__ x1, float* __restrict__ x2,
    const float* __restrict__ Wsg, const float* __restrict__ Wmg,
    const float* __restrict__ Wkg,
    float* __restrict__ Ws_l,   // [DOUT*DIN] unpadded (uniform/broadcast reads)
    float* __restrict__ Wm_l,   // [32*33] padded rows
    float* __restrict__ Wk_l,   // [32*33] padded rows
    float* __restrict__ Abuf,   // [64*33]
    float* __restrict__ Bbuf,   // [32*33]
    float* __restrict__ msgk,   // [32*33]
    int t, int k, int m1, int m2, int lane)
{
    // ---- phase 0: stage weights to LDS, zero msg_k accumulator ----
    for (int i = t; i < DOUT * DIN; i += NTHREADS) {
        const int h = i / DIN, d = i % DIN;
        Ws_l[i] = Wsg[i];
        Wm_l[h * 33 + d] = Wmg[i];
        Wk_l[h * 33 + d] = Wkg[i];
    }
    for (int i = t; i < 32 * 33; i += NTHREADS) msgk[i] = 0.0f;
    __syncthreads();

    // ---- phase 1a: msg_k contribution (low register pressure first) ----
    // Thread holds antennas m1, m1+32 for user k; lane^32 holds m1+1, m1+33;
    // 16 waves cover all 64 antennas via LDS fp32 atomics.
#pragma unroll
    for (int d = 0; d < DIN; ++d) {
        float s = x1[d] + x2[d];
        s += __shfl_xor(s, 32);
        if (lane < 32) atomicAdd(&msgk[k * 33 + d], s);
    }

    // ---- phase 1b: msg_m butterfly per node, fused A = Wm*msg_m ----
    {
        float mm[DIN];
#pragma unroll
        for (int d = 0; d < DIN; ++d) mm[d] = x1[d];
#pragma unroll
        for (int mask = 1; mask <= 16; mask <<= 1) {
#pragma unroll
            for (int d = 0; d < DIN; ++d) mm[d] += __shfl_xor(mm[d], mask);
        }
        if (k < DOUT) {
            float acc = 0.0f;
#pragma unroll
            for (int d = 0; d < DIN; ++d) acc += Wm_l[k * 33 + d] * mm[d];
            Abuf[m1 * 33 + k] = acc;
        }
    }
    {
        float mm[DIN];
#pragma unroll
        for (int d = 0; d < DIN; ++d) mm[d] = x2[d];
#pragma unroll
        for (int mask = 1; mask <= 16; mask <<= 1) {
#pragma unroll
            for (int d = 0; d < DIN; ++d) mm[d] += __shfl_xor(mm[d], mask);
        }
        if (k < DOUT) {
            float acc = 0.0f;
#pragma unroll
            for (int d = 0; d < DIN; ++d) acc += Wm_l[k * 33 + d] * mm[d];
            Abuf[m2 * 33 + k] = acc;
        }
    }
    __syncthreads();

    // ---- phase 2: B[k][h] = Wk * msg_k ----
    if (t < 32 * DOUT) {
        const int kk = t / DOUT, hh = t % DOUT;
        float acc = 0.0f;
#pragma unroll
        for (int d = 0; d < DIN; ++d) acc += Wk_l[hh * 33 + d] * msgk[kk * 33 + d];
        Bbuf[kk * 33 + hh] = acc;
    }
    __syncthreads();

    // ---- phase 3: per-node z = Ws*x + A[m] + B[k], relu, x <- z ----
    {
        float z[DOUT];
#pragma unroll
        for (int h = 0; h < DOUT; ++h) {
            float acc = Abuf[m1 * 33 + h] + Bbuf[k * 33 + h];
            if constexpr (DIN >= 4) {
                const float4* wr = reinterpret_cast<const float4*>(Ws_l + h * DIN);
#pragma unroll
                for (int q = 0; q < DIN / 4; ++q) {
                    const float4 w = wr[q];
                    acc += w.x * x1[4 * q] + w.y * x1[4 * q + 1]
                         + w.z * x1[4 * q + 2] + w.w * x1[4 * q + 3];
                }
            } else {
#pragma unroll
                for (int d = 0; d < DIN; ++d) acc += Ws_l[h * DIN + d] * x1[d];
            }
            z[h] = RELU ? fmaxf(acc, 0.0f) : acc;
        }
#pragma unroll
        for (int h = 0; h < DOUT; ++h) x1[h] = z[h];

#pragma unroll
        for (int h = 0; h < DOUT; ++h) {
            float acc = Abuf[m2 * 33 + h] + Bbuf[k * 33 + h];
            if constexpr (DIN >= 4) {
                const float4* wr = reinterpret_cast<const float4*>(Ws_l + h * DIN);
#pragma unroll
                for (int q = 0; q < DIN / 4; ++q) {
                    const float4 w = wr[q];
                    acc += w.x * x2[4 * q] + w.y * x2[4 * q + 1]
                         + w.z * x2[4 * q + 2] + w.w * x2[4 * q + 3];
                }
            } else {
#pragma unroll
                for (int d = 0; d < DIN; ++d) acc += Ws_l[h * DIN + d] * x2[d];
            }
            z[h] = RELU ? fmaxf(acc, 0.0f) : acc;
        }
#pragma unroll
        for (int h = 0; h < DOUT; ++h) x2[h] = z[h];
    }
    __syncthreads();  // protect W/msgk LDS before next layer restages
}

__global__ __launch_bounds__(NTHREADS, 4) void gnn_fused(
    const float* __restrict__ xg,
    const float* __restrict__ w1s, const float* __restrict__ w1m, const float* __restrict__ w1k,
    const float* __restrict__ w2s, const float* __restrict__ w2m, const float* __restrict__ w2k,
    const float* __restrict__ w3s, const float* __restrict__ w3m, const float* __restrict__ w3k,
    const float* __restrict__ w4s, const float* __restrict__ w4m, const float* __restrict__ w4k,
    const float* __restrict__ w5s, const float* __restrict__ w5m, const float* __restrict__ w5k,
    float* __restrict__ out)
{
    __shared__ float Ws_l[32 * 32];
    __shared__ float Wm_l[32 * 33];
    __shared__ float Wk_l[32 * 33];
    __shared__ float Abuf[64 * 33];
    __shared__ float Bbuf[32 * 33];
    __shared__ float msgk[32 * 33];
    __shared__ float red[17];

    const int t = threadIdx.x;
    const int b = blockIdx.x;
    const int k = t & 31;
    const int m1 = t >> 5;
    const int m2 = m1 + 32;
    const int lane = t & 63;
    const int wave = t >> 6;

    float x1[32], x2[32];

    // input: (b, 64, 32, 2) -> node n covers floats [2n, 2n+1]
    const float2 a1 = *reinterpret_cast<const float2*>(xg + (size_t)b * 4096 + 2 * t);
    const float2 a2 = *reinterpret_cast<const float2*>(xg + (size_t)b * 4096 + 2048 + 2 * t);
    x1[0] = a1.x; x1[1] = a1.y;
    x2[0] = a2.x; x2[1] = a2.y;

    gnn_layer_dev<2, 32, true>(x1, x2, w1s, w1m, w1k,
                               Ws_l, Wm_l, Wk_l, Abuf, Bbuf, msgk, t, k, m1, m2, lane);

#pragma unroll 1
    for (int l = 0; l < 3; ++l) {
        const float* ws = (l == 0) ? w2s : (l == 1) ? w3s : w4s;
        const float* wm = (l == 0) ? w2m : (l == 1) ? w3m : w4m;
        const float* wk = (l == 0) ? w2k : (l == 1) ? w3k : w4k;
        gnn_layer_dev<32, 32, true>(x1, x2, ws, wm, wk,
                                    Ws_l, Wm_l, Wk_l, Abuf, Bbuf, msgk, t, k, m1, m2, lane);
    }

    gnn_layer_dev<32, 2, false>(x1, x2, w5s, w5m, w5k,
                                Ws_l, Wm_l, Wk_l, Abuf, Bbuf, msgk, t, k, m1, m2, lane);

    // ---- pwr_norm: alpha = rsqrt(sum over all (m,k,c) of z^2) ----
    float p = x1[0] * x1[0] + x1[1] * x1[1] + x2[0] * x2[0] + x2[1] * x2[1];
#pragma unroll
    for (int mask = 1; mask <= 32; mask <<= 1) p += __shfl_xor(p, mask);
    if (lane == 0) red[wave] = p;
    __syncthreads();
    if (t == 0) {
        float tot = 0.0f;
#pragma unroll
        for (int i = 0; i < 16; ++i) tot += red[i];
        red[16] = rsqrtf(tot);
    }
    __syncthreads();
    const float alpha = red[16];

    float2 o1, o2;
    o1.x = alpha * x1[0]; o1.y = alpha * x1[1];
    o2.x = alpha * x2[0]; o2.y = alpha * x2[1];
    *reinterpret_cast<float2*>(out + (size_t)b * 4096 + 2 * t) = o1;
    *reinterpret_cast<float2*>(out + (size_t)b * 4096 + 2048 + 2 * t) = o2;
}

}  // namespace

extern "C" void kernel_launch(void* const* d_in, const int* in_sizes, int n_in,
                              void* d_out, int out_size, void* d_ws, size_t ws_size,
                              hipStream_t stream) {
    const float* xg  = (const float*)d_in[0];
    const float* w1s = (const float*)d_in[1];
    const float* w1m = (const float*)d_in[2];
    const float* w1k = (const float*)d_in[3];
    const float* w2s = (const float*)d_in[4];
    const float* w2m = (const float*)d_in[5];
    const float* w2k = (const float*)d_in[6];
    const float* w3s = (const float*)d_in[7];
    const float* w3m = (const float*)d_in[8];
    const float* w3k = (const float*)d_in[9];
    const float* w4s = (const float*)d_in[10];
    const float* w4m = (const float*)d_in[11];
    const float* w4k = (const float*)d_in[12];
    const float* w5s = (const float*)d_in[13];
    const float* w5m = (const float*)d_in[14];
    const float* w5k = (const float*)d_in[15];
    float* out = (float*)d_out;

    hipLaunchKernelGGL(gnn_fused, dim3(1024), dim3(NTHREADS), 0, stream,
                       xg, w1s, w1m, w1k, w2s, w2m, w2k, w3s, w3m, w3k,
                       w4s, w4m, w4k, w5s, w5m, w5k, out);
}

// Round 3
// 1884.354 us; speedup vs baseline: 5.5736x; 1.2676x over previous
//
#include <hip/hip_runtime.h>

// Precoding GNN: 5 layers of z = Ws*x + Wm*(sum_k x) + Wk*(sum_m x), ReLU(1-4),
// then Frobenius power normalization per batch item.
// M=64 antennas, K=32 users, D=32 hidden, BS=1024.
//
// One 1024-thread block per batch item. Thread t owns nodes t and t+1024
// (node n = m*32+k), features in registers, fp32 end-to-end.
//
// R1 lesson: default launch_bounds -> 64-VGPR budget -> spill -> 34 GB HBM.
// R2 lesson: float[32] allocas were never SROA'd (VGPR stayed 64, 6.5 GB
//   scratch traffic). Fix: ext_vector_type(32) registers (whole-vector
//   load/store -> mem2reg promotes without SROA), and read Ws directly from
//   the __restrict const kernel arg with constant offsets (uniform -> s_load
//   into SGPRs) instead of LDS broadcast reads.

namespace {

constexpr int NTHREADS = 1024;
constexpr int LD = 34;   // LDS row stride: 8B-aligned (float2), bank stride 2 -> conflict-free

typedef float vf32 __attribute__((ext_vector_type(32)));

template <int DIN, int DOUT, bool RELU>
__device__ __forceinline__ void gnn_layer_dev(
    vf32& x1, vf32& x2,
    const float* __restrict__ Wsg, const float* __restrict__ Wmg,
    const float* __restrict__ Wkg,
    float* __restrict__ Wm_l,   // [32*LD]
    float* __restrict__ Wk_l,   // [32*LD]
    float* __restrict__ Abuf,   // [64*LD]
    float* __restrict__ Bbuf,   // [32*LD]
    float* __restrict__ msgk,   // [32*LD]
    int t, int k, int m1, int m2, int lane)
{
    // ---- phase 0: stage Wm/Wk to LDS (per-lane-row access later), zero msgk ----
    for (int i = t; i < DOUT * DIN; i += NTHREADS) {
        const int h = i / DIN, d = i % DIN;
        Wm_l[h * LD + d] = Wmg[i];
        Wk_l[h * LD + d] = Wkg[i];
    }
    for (int i = t; i < 32 * LD; i += NTHREADS) msgk[i] = 0.0f;
    __syncthreads();

    // ---- phase 1a: msg_k contribution (register-light first) ----
    // Thread holds antennas m1, m1+32 for user k; lane^32 holds m1^1 pair;
    // 16 waves cover all 64 antennas via LDS ds_add_f32.
#pragma unroll
    for (int d = 0; d < DIN; ++d) {
        float s = x1[d] + x2[d];
        s += __shfl_xor(s, 32);
        if (lane < 32) atomicAdd(&msgk[k * LD + d], s);
    }

    // ---- phase 1b: msg_m butterfly per node, fused A[m][k] = Wm[k,:].msg_m ----
    {
        vf32 mm = x1;
#pragma unroll
        for (int mask = 1; mask <= 16; mask <<= 1) {
#pragma unroll
            for (int d = 0; d < DIN; ++d) mm[d] += __shfl_xor(mm[d], mask);
        }
        if (k < DOUT) {
            const float2* wr = reinterpret_cast<const float2*>(Wm_l + k * LD);
            float acc = 0.0f;
#pragma unroll
            for (int q = 0; q < (DIN + 1) / 2; ++q) {
                const float2 w = wr[q];
                acc += w.x * mm[2 * q];
                if (2 * q + 1 < DIN) acc += w.y * mm[2 * q + 1];
            }
            Abuf[m1 * LD + k] = acc;
        }
    }
    {
        vf32 mm = x2;
#pragma unroll
        for (int mask = 1; mask <= 16; mask <<= 1) {
#pragma unroll
            for (int d = 0; d < DIN; ++d) mm[d] += __shfl_xor(mm[d], mask);
        }
        if (k < DOUT) {
            const float2* wr = reinterpret_cast<const float2*>(Wm_l + k * LD);
            float acc = 0.0f;
#pragma unroll
            for (int q = 0; q < (DIN + 1) / 2; ++q) {
                const float2 w = wr[q];
                acc += w.x * mm[2 * q];
                if (2 * q + 1 < DIN) acc += w.y * mm[2 * q + 1];
            }
            Abuf[m2 * LD + k] = acc;
        }
    }
    __syncthreads();

    // ---- phase 2: B[k][h] = Wk[h,:].msg_k ----
    if (t < 32 * DOUT) {
        const int kk = t / DOUT, hh = t % DOUT;
        const float2* wr = reinterpret_cast<const float2*>(Wk_l + hh * LD);
        const float2* mr = reinterpret_cast<const float2*>(msgk + kk * LD);
        float acc = 0.0f;
#pragma unroll
        for (int q = 0; q < (DIN + 1) / 2; ++q) {
            const float2 w = wr[q];
            const float2 m = mr[q];
            acc += w.x * m.x;
            if (2 * q + 1 < DIN) acc += w.y * m.y;
        }
        Bbuf[kk * LD + hh] = acc;
    }
    __syncthreads();

    // ---- phase 3: per-node z[h] = Ws[h,:].x + A[m][h] + B[k][h]; Ws read
    //      straight from global (uniform address -> scalar loads/SGPRs) ----
    {
        vf32 z;
        const float2* ar = reinterpret_cast<const float2*>(Abuf + m1 * LD);
        const float2* br = reinterpret_cast<const float2*>(Bbuf + k * LD);
#pragma unroll
        for (int hq = 0; hq < DOUT / 2; ++hq) {
            const float2 av = ar[hq];
            const float2 bv = br[hq];
            float acc0 = av.x + bv.x;
            float acc1 = av.y + bv.y;
#pragma unroll
            for (int d = 0; d < DIN; ++d) {
                const float xd = x1[d];
                acc0 += Wsg[(2 * hq) * DIN + d] * xd;
                acc1 += Wsg[(2 * hq + 1) * DIN + d] * xd;
            }
            z[2 * hq]     = RELU ? fmaxf(acc0, 0.0f) : acc0;
            z[2 * hq + 1] = RELU ? fmaxf(acc1, 0.0f) : acc1;
        }
        x1 = z;
    }
    {
        vf32 z;
        const float2* ar = reinterpret_cast<const float2*>(Abuf + m2 * LD);
        const float2* br = reinterpret_cast<const float2*>(Bbuf + k * LD);
#pragma unroll
        for (int hq = 0; hq < DOUT / 2; ++hq) {
            const float2 av = ar[hq];
            const float2 bv = br[hq];
            float acc0 = av.x + bv.x;
            float acc1 = av.y + bv.y;
#pragma unroll
            for (int d = 0; d < DIN; ++d) {
                const float xd = x2[d];
                acc0 += Wsg[(2 * hq) * DIN + d] * xd;
                acc1 += Wsg[(2 * hq + 1) * DIN + d] * xd;
            }
            z[2 * hq]     = RELU ? fmaxf(acc0, 0.0f) : acc0;
            z[2 * hq + 1] = RELU ? fmaxf(acc1, 0.0f) : acc1;
        }
        x2 = z;
    }
    __syncthreads();  // protect Wm/Wk/msgk before next layer restages
}

__global__ __launch_bounds__(NTHREADS, 4) void gnn_fused(
    const float* __restrict__ xg,
    const float* __restrict__ w1s, const float* __restrict__ w1m, const float* __restrict__ w1k,
    const float* __restrict__ w2s, const float* __restrict__ w2m, const float* __restrict__ w2k,
    const float* __restrict__ w3s, const float* __restrict__ w3m, const float* __restrict__ w3k,
    const float* __restrict__ w4s, const float* __restrict__ w4m, const float* __restrict__ w4k,
    const float* __restrict__ w5s, const float* __restrict__ w5m, const float* __restrict__ w5k,
    float* __restrict__ out)
{
    __shared__ float Wm_l[32 * LD];
    __shared__ float Wk_l[32 * LD];
    __shared__ float Abuf[64 * LD];
    __shared__ float Bbuf[32 * LD];
    __shared__ float msgk[32 * LD];
    __shared__ float red[17];

    const int t = threadIdx.x;
    const int b = blockIdx.x;
    const int k = t & 31;
    const int m1 = t >> 5;
    const int m2 = m1 + 32;
    const int lane = t & 63;
    const int wave = t >> 6;

    vf32 x1, x2;

    // input: (b, 64, 32, 2) -> node n covers floats [2n, 2n+1]
    const float2 a1 = *reinterpret_cast<const float2*>(xg + (size_t)b * 4096 + 2 * t);
    const float2 a2 = *reinterpret_cast<const float2*>(xg + (size_t)b * 4096 + 2048 + 2 * t);
    x1[0] = a1.x; x1[1] = a1.y;
    x2[0] = a2.x; x2[1] = a2.y;

    gnn_layer_dev<2, 32, true>(x1, x2, w1s, w1m, w1k,
                               Wm_l, Wk_l, Abuf, Bbuf, msgk, t, k, m1, m2, lane);
    gnn_layer_dev<32, 32, true>(x1, x2, w2s, w2m, w2k,
                                Wm_l, Wk_l, Abuf, Bbuf, msgk, t, k, m1, m2, lane);
    gnn_layer_dev<32, 32, true>(x1, x2, w3s, w3m, w3k,
                                Wm_l, Wk_l, Abuf, Bbuf, msgk, t, k, m1, m2, lane);
    gnn_layer_dev<32, 32, true>(x1, x2, w4s, w4m, w4k,
                                Wm_l, Wk_l, Abuf, Bbuf, msgk, t, k, m1, m2, lane);
    gnn_layer_dev<32, 2, false>(x1, x2, w5s, w5m, w5k,
                                Wm_l, Wk_l, Abuf, Bbuf, msgk, t, k, m1, m2, lane);

    // ---- pwr_norm: alpha = rsqrt(sum over all (m,k,c) of z^2) ----
    float p = x1[0] * x1[0] + x1[1] * x1[1] + x2[0] * x2[0] + x2[1] * x2[1];
#pragma unroll
    for (int mask = 1; mask <= 32; mask <<= 1) p += __shfl_xor(p, mask);
    if (lane == 0) red[wave] = p;
    __syncthreads();
    if (t == 0) {
        float tot = 0.0f;
#pragma unroll
        for (int i = 0; i < 16; ++i) tot += red[i];
        red[16] = rsqrtf(tot);
    }
    __syncthreads();
    const float alpha = red[16];

    float2 o1, o2;
    o1.x = alpha * x1[0]; o1.y = alpha * x1[1];
    o2.x = alpha * x2[0]; o2.y = alpha * x2[1];
    *reinterpret_cast<float2*>(out + (size_t)b * 4096 + 2 * t) = o1;
    *reinterpret_cast<float2*>(out + (size_t)b * 4096 + 2048 + 2 * t) = o2;
}

}  // namespace

extern "C" void kernel_launch(void* const* d_in, const int* in_sizes, int n_in,
                              void* d_out, int out_size, void* d_ws, size_t ws_size,
                              hipStream_t stream) {
    const float* xg  = (const float*)d_in[0];
    const float* w1s = (const float*)d_in[1];
    const float* w1m = (const float*)d_in[2];
    const float* w1k = (const float*)d_in[3];
    const float* w2s = (const float*)d_in[4];
    const float* w2m = (const float*)d_in[5];
    const float* w2k = (const float*)d_in[6];
    const float* w3s = (const float*)d_in[7];
    const float* w3m = (const float*)d_in[8];
    const float* w3k = (const float*)d_in[9];
    const float* w4s = (const float*)d_in[10];
    const float* w4m = (const float*)d_in[11];
    const float* w4k = (const float*)d_in[12];
    const float* w5s = (const float*)d_in[13];
    const float* w5m = (const float*)d_in[14];
    const float* w5k = (const float*)d_in[15];
    float* out = (float*)d_out;

    hipLaunchKernelGGL(gnn_fused, dim3(1024), dim3(NTHREADS), 0, stream,
                       xg, w1s, w1m, w1k, w2s, w2m, w2k, w3s, w3m, w3k,
                       w4s, w4m, w4k, w5s, w5m, w5k, out);
}